// Round 12
// baseline (256.286 us; speedup 1.0000x reference)
//
#include <hip/hip_runtime.h>
#include <hip/hip_fp16.h>

#define FIN 128
#define F1 256      // H1*D1
#define H1N 8
#define D1N 32
#define NCLS 40
#define FT2P 64     // padded row stride for ft2 (halves)
#define W2PITCH 258 // LDS pitch (halves) >= 256! dword-bank=(c+2k)%32 -> worst 2-way (free)
#define NEG 0.2f

static __device__ __forceinline__ float leaky(float x){ return x >= 0.f ? x : NEG*x; }

// ---------------- CSR build ----------------
__global__ void k_hist(const int* __restrict__ dst, int* __restrict__ deg, int E){
    int e = blockIdx.x*256 + threadIdx.x;
    if (e < E) atomicAdd(&deg[dst[e]], 1);
}

__global__ void k_scan1(const int* __restrict__ deg, int* __restrict__ rowptr,
                        int* __restrict__ bsum, int n){
    __shared__ int s[256];
    int t = threadIdx.x;
    int i = blockIdx.x*256 + t;
    int v = (i < n) ? deg[i] : 0;
    s[t] = v;
    __syncthreads();
    for (int off=1; off<256; off<<=1){
        int y = (t >= off) ? s[t-off] : 0;
        __syncthreads();
        if (t >= off) s[t] += y;
        __syncthreads();
    }
    if (i < n) rowptr[i] = s[t] - v;          // exclusive, pre-offset
    if (t == 255) bsum[blockIdx.x] = s[255];
}

__global__ void k_scan2(int* __restrict__ rowptr, const int* __restrict__ bsum,
                        int n, int E){
    int b = blockIdx.x;
    int l = threadIdx.x & 63;
    int v = 0;
    for (int j = l; j < b; j += 64) v += bsum[j];
    for (int msk=1; msk<64; msk<<=1) v += __shfl_xor(v, msk);
    int i = b*256 + threadIdx.x;
    if (i < n) rowptr[i] += v;
    else if (i == n) rowptr[n] = E;
}

__global__ void k_scatter(const int* __restrict__ src, const int* __restrict__ dst,
                          const int* __restrict__ rowptr, int* __restrict__ deg,
                          int* __restrict__ adj, int E){
    int e = blockIdx.x*256 + threadIdx.x;
    if (e < E){
        int d = dst[e];
        int pos = atomicSub(&deg[d], 1) - 1;
        adj[rowptr[d] + pos] = src[e];
    }
}

// ---------------- GEMM1: [M,128]@[128,256] -> fp16 FT + fused el/er ----------------
__global__ __launch_bounds__(256) void k_gemm1(const float* __restrict__ X,
                                               const float* __restrict__ W,
                                               const float* __restrict__ al,
                                               const float* __restrict__ ar,
                                               __half* __restrict__ FT,
                                               float* __restrict__ el,
                                               float* __restrict__ er, int M){
    __shared__ float As[32][68];   // As[k][m]
    __shared__ float Bs[32][68];   // Bs[k][n]
    int t = threadIdx.x;
    int bx = blockIdx.x & 3;
    int by = blockIdx.x >> 2;
    int m0 = by*64, n0 = bx*64;
    int ty = t >> 4, tx = t & 15;
    float acc[4][4] = {};
    for (int k0 = 0; k0 < FIN; k0 += 32){
        #pragma unroll
        for (int p=0;p<2;p++){
            int f = t + p*256;
            int m = f >> 3;
            int kq = f & 7;
            int row = m0 + m;
            float4 v = make_float4(0.f,0.f,0.f,0.f);
            if (row < M) v = *(const float4*)&X[row*FIN + k0 + kq*4];
            As[kq*4+0][m] = v.x; As[kq*4+1][m] = v.y;
            As[kq*4+2][m] = v.z; As[kq*4+3][m] = v.w;
        }
        #pragma unroll
        for (int p=0;p<2;p++){
            int f = t + p*256;
            int kk = f >> 4;
            int nq = f & 15;
            float4 v = *(const float4*)&W[(size_t)(k0+kk)*F1 + n0 + nq*4];
            *(float4*)&Bs[kk][nq*4] = v;
        }
        __syncthreads();
        #pragma unroll
        for (int kk=0; kk<32; kk++){
            float4 a4 = *(const float4*)&As[kk][ty*4];
            float4 b4 = *(const float4*)&Bs[kk][tx*4];
            float av[4] = {a4.x,a4.y,a4.z,a4.w};
            float bv[4] = {b4.x,b4.y,b4.z,b4.w};
            #pragma unroll
            for (int r=0;r<4;r++)
                #pragma unroll
                for (int c=0;c<4;c++)
                    acc[r][c] = fmaf(av[r], bv[c], acc[r][c]);
        }
        __syncthreads();
    }
    // fused el/er: head h spans 32 cols; this thread's 4 cols lie in one head
    int h = (bx<<1) + (tx>>3);
    int basew = h*D1N + (tx&7)*4;
    float4 wl = *(const float4*)&al[basew];
    float4 wr = *(const float4*)&ar[basew];
    float pl[4], pr[4];
    #pragma unroll
    for (int r=0;r<4;r++){
        pl[r] = acc[r][0]*wl.x + acc[r][1]*wl.y + acc[r][2]*wl.z + acc[r][3]*wl.w;
        pr[r] = acc[r][0]*wr.x + acc[r][1]*wr.y + acc[r][2]*wr.z + acc[r][3]*wr.w;
    }
    #pragma unroll
    for (int msk=1; msk<8; msk<<=1){
        #pragma unroll
        for (int r=0;r<4;r++){
            pl[r] += __shfl_xor(pl[r], msk);
            pr[r] += __shfl_xor(pr[r], msk);
        }
    }
    #pragma unroll
    for (int r=0;r<4;r++){
        int row = m0 + ty*4 + r;
        if (row < M){
            union { uint2 u; __half2 h2[2]; } P;
            P.h2[0] = __floats2half2_rn(acc[r][0], acc[r][1]);
            P.h2[1] = __floats2half2_rn(acc[r][2], acc[r][3]);
            *(uint2*)&FT[(size_t)row*F1 + n0 + tx*4] = P.u;
            if ((tx & 7) == 0){
                el[row*H1N + h] = pl[r];
                er[row*H1N + h] = pr[r];
            }
        }
    }
}

// ---- layer-1 single-pass softmax + agg + relu + fused GEMM2/el2/er2 ----
// 2 nodes interleaved per wave: doubles in-flight gather chains (latency hiding)
__global__ __launch_bounds__(512) void k_agg1(const __half* __restrict__ FT,
                      const float* __restrict__ el, const float* __restrict__ er,
                      const float* __restrict__ W2,      // [256][40] fp32
                      const float* __restrict__ al2, const float* __restrict__ ar2,
                      const int* __restrict__ rowptr, const int* __restrict__ adj,
                      __half* __restrict__ FT2, float* __restrict__ el2,
                      float* __restrict__ er2, int n, int nwTot){
    __shared__ __half W2h[40*W2PITCH];   // transposed: W2h[c][k], ~20.2 KB
    __shared__ float  hst[8][260];       // per-wave h-row staging
    int t = threadIdx.x;
    for (int e = t; e < 256*40; e += 512){
        int k = e / 40, c = e - k*40;
        W2h[c*W2PITCH + k] = __float2half_rn(W2[e]);
    }
    __syncthreads();

    int w = t >> 6, l = t & 63;
    int h2 = l >> 3;                   // head owning elements [4l,4l+4)
    int c = (l < 40) ? l : (l - 40);
    float keep = (l < NCLS) ? 1.f : 0.f;
    float a2l = al2[c], a2r = ar2[c];
    const __half* wrow = &W2h[c*W2PITCH];
    float* hp = &hst[w][0];

    // epilogue helper (h row staged in hp; node output to FT2/el2/er2)
    auto epilogue = [&](int node, float ax, float ay, float az, float aw){
        *(float4*)&hp[l*4] = make_float4(ax, ay, az, aw);
        __builtin_amdgcn_wave_barrier();
        asm volatile("s_waitcnt lgkmcnt(0)" ::: "memory");
        float o0=0.f, o1=0.f, o2=0.f, o3=0.f;
        #pragma unroll
        for (int k0 = 0; k0 < 64; k0 += 4){
            {   float4 hv = *(const float4*)&hp[k0*4];
                float2 fa = __half22float2(*(const __half2*)&wrow[k0*4]);
                float2 fb = __half22float2(*(const __half2*)&wrow[k0*4+2]);
                o0 = fmaf(hv.x, fa.x, o0); o0 = fmaf(hv.y, fa.y, o0);
                o0 = fmaf(hv.z, fb.x, o0); o0 = fmaf(hv.w, fb.y, o0); }
            {   float4 hv = *(const float4*)&hp[(k0+1)*4];
                float2 fa = __half22float2(*(const __half2*)&wrow[(k0+1)*4]);
                float2 fb = __half22float2(*(const __half2*)&wrow[(k0+1)*4+2]);
                o1 = fmaf(hv.x, fa.x, o1); o1 = fmaf(hv.y, fa.y, o1);
                o1 = fmaf(hv.z, fb.x, o1); o1 = fmaf(hv.w, fb.y, o1); }
            {   float4 hv = *(const float4*)&hp[(k0+2)*4];
                float2 fa = __half22float2(*(const __half2*)&wrow[(k0+2)*4]);
                float2 fb = __half22float2(*(const __half2*)&wrow[(k0+2)*4+2]);
                o2 = fmaf(hv.x, fa.x, o2); o2 = fmaf(hv.y, fa.y, o2);
                o2 = fmaf(hv.z, fb.x, o2); o2 = fmaf(hv.w, fb.y, o2); }
            {   float4 hv = *(const float4*)&hp[(k0+3)*4];
                float2 fa = __half22float2(*(const __half2*)&wrow[(k0+3)*4]);
                float2 fb = __half22float2(*(const __half2*)&wrow[(k0+3)*4+2]);
                o3 = fmaf(hv.x, fa.x, o3); o3 = fmaf(hv.y, fa.y, o3);
                o3 = fmaf(hv.z, fb.x, o3); o3 = fmaf(hv.w, fb.y, o3); }
        }
        float out = (o0 + o1) + (o2 + o3);
        __builtin_amdgcn_wave_barrier();
        float pl = keep * out * a2l;
        float pr = keep * out * a2r;
        #pragma unroll
        for (int msk=1; msk<64; msk<<=1){
            pl += __shfl_xor(pl, msk);
            pr += __shfl_xor(pr, msk);
        }
        if (l == 0){ el2[node] = pl; er2[node] = pr; }
        if (l < NCLS) FT2[(size_t)node*FT2P + l] = __float2half_rn(out);
    };

    for (int nA = blockIdx.x*8 + w; nA < n; nA += 2*nwTot){
        int nB = nA + nwTot;
        bool hasB = (nB < n);
        int rsA = rowptr[nA];
        int degA = rowptr[nA+1] - rsA;
        int rsB = 0, degB = 0;
        if (hasB){ rsB = rowptr[nB]; degB = rowptr[nB+1] - rsB; }
        float erA = er[nA*H1N + h2];
        float erB = hasB ? er[nB*H1N + h2] : 0.f;

        float ssA = 0.f, ssB = 0.f;
        float axA=0.f, ayA=0.f, azA=0.f, awA=0.f;
        float axB=0.f, ayB=0.f, azB=0.f, awB=0.f;

        int nbat = (degA + 7) >> 3;
        int nbB  = (degB + 7) >> 3;
        if (nbB > nbat) nbat = nbB;
        for (int b = 0; b < nbat; b++){
            int j = b*8;
            int svA[8], svB[8];
            #pragma unroll
            for (int i=0;i<8;i++) svA[i] = (j+i < degA) ? adj[rsA+j+i] : -1;
            #pragma unroll
            for (int i=0;i<8;i++) svB[i] = (j+i < degB) ? adj[rsB+j+i] : -1;
            float aA[8], aB[8];
            #pragma unroll
            for (int i=0;i<8;i++){
                aA[i] = (svA[i] >= 0) ? __expf(leaky(el[svA[i]*H1N + h2] + erA)) : 0.f;
                ssA += aA[i];
            }
            #pragma unroll
            for (int i=0;i<8;i++){
                aB[i] = (svB[i] >= 0) ? __expf(leaky(el[svB[i]*H1N + h2] + erB)) : 0.f;
                ssB += aB[i];
            }
            #pragma unroll
            for (int i=0;i<8;i++){
                if (svA[i] >= 0){
                    union { uint2 u; __half2 h2v[2]; } U;
                    U.u = *(const uint2*)&FT[(size_t)svA[i]*F1 + l*4];
                    float2 f01 = __half22float2(U.h2v[0]);
                    float2 f23 = __half22float2(U.h2v[1]);
                    axA = fmaf(aA[i], f01.x, axA); ayA = fmaf(aA[i], f01.y, ayA);
                    azA = fmaf(aA[i], f23.x, azA); awA = fmaf(aA[i], f23.y, awA);
                }
            }
            #pragma unroll
            for (int i=0;i<8;i++){
                if (svB[i] >= 0){
                    union { uint2 u; __half2 h2v[2]; } U;
                    U.u = *(const uint2*)&FT[(size_t)svB[i]*F1 + l*4];
                    float2 f01 = __half22float2(U.h2v[0]);
                    float2 f23 = __half22float2(U.h2v[1]);
                    axB = fmaf(aB[i], f01.x, axB); ayB = fmaf(aB[i], f01.y, ayB);
                    azB = fmaf(aB[i], f23.x, azB); awB = fmaf(aB[i], f23.y, awB);
                }
            }
        }
        {
            float inv = 1.f / fmaxf(ssA, 1e-16f);
            epilogue(nA, fmaxf(axA*inv,0.f), fmaxf(ayA*inv,0.f),
                         fmaxf(azA*inv,0.f), fmaxf(awA*inv,0.f));
        }
        if (hasB){
            float inv = 1.f / fmaxf(ssB, 1e-16f);
            epilogue(nB, fmaxf(axB*inv,0.f), fmaxf(ayB*inv,0.f),
                         fmaxf(azB*inv,0.f), fmaxf(awB*inv,0.f));
        }
    }
}

// ---------------- layer-2 single-pass softmax + aggregation ----------------
__global__ __launch_bounds__(256) void k_agg2(const __half* __restrict__ FT2,
                      const float* __restrict__ el, const float* __restrict__ er,
                      const int* __restrict__ rowptr, const int* __restrict__ adj,
                      float* __restrict__ out, int n){
    int node = (blockIdx.x*256 + threadIdx.x) >> 6;
    int l = threadIdx.x & 63;
    if (node >= n) return;
    int rs = rowptr[node];
    int deg = rowptr[node+1] - rs;
    float ern = er[node];
    float ssum = 0.f, acc = 0.f;
    int j = 0;
    for (; j + 8 <= deg; j += 8){
        int sv[8];
        #pragma unroll
        for (int i=0;i<8;i++) sv[i] = adj[rs+j+i];
        float av[8];
        #pragma unroll
        for (int i=0;i<8;i++){
            av[i] = __expf(leaky(el[sv[i]] + ern));
            ssum += av[i];
        }
        if (l < NCLS){
            #pragma unroll
            for (int i=0;i<8;i++){
                float f = __half2float(FT2[(size_t)sv[i]*FT2P + l]);
                acc = fmaf(av[i], f, acc);
            }
        }
    }
    for (; j < deg; j++){
        int s = adj[rs + j];
        float a = __expf(leaky(el[s] + ern));
        ssum += a;
        if (l < NCLS) acc = fmaf(a, __half2float(FT2[(size_t)s*FT2P + l]), acc);
    }
    if (l < NCLS) out[(size_t)node*NCLS + l] = acc / fmaxf(ssum, 1e-16f);
}

extern "C" void kernel_launch(void* const* d_in, const int* in_sizes, int n_in,
                              void* d_out, int out_size, void* d_ws, size_t ws_size,
                              hipStream_t stream){
    const float* x   = (const float*)d_in[0];
    const float* W1  = (const float*)d_in[1];
    const float* al1 = (const float*)d_in[2];
    const float* ar1 = (const float*)d_in[3];
    const float* W2  = (const float*)d_in[4];
    const float* al2 = (const float*)d_in[5];
    const float* ar2 = (const float*)d_in[6];
    const int*   src = (const int*)d_in[7];
    const int*   dst = (const int*)d_in[8];
    int E = in_sizes[7];
    int n = in_sizes[0] / FIN;   // 20000

    char* ws = (char*)d_ws;
    size_t off = 0;
    auto alloc = [&](size_t bytes)->void*{
        void* p = ws + off; off += (bytes + 255) & ~(size_t)255; return p;
    };
    __half* ft1h  = (__half*)alloc((size_t)n*F1*2);
    __half* ft2h  = (__half*)alloc((size_t)n*FT2P*2);
    float*  el1   = (float*)alloc((size_t)n*H1N*4);
    float*  er1   = (float*)alloc((size_t)n*H1N*4);
    float*  el2   = (float*)alloc((size_t)n*4);
    float*  er2   = (float*)alloc((size_t)n*4);
    int*    rowptr= (int*)alloc((size_t)(n+1)*4);
    int*    adj   = (int*)alloc((size_t)E*4);
    int*    bsum  = (int*)alloc((size_t)((n+255)/256)*4);
    int*    deg   = (int*)alloc((size_t)n*4);

    int nb_e = (E + 255)/256;
    int nb_n = (n + 255)/256;

    hipMemsetAsync(deg, 0, (size_t)n*4, stream);
    k_hist   <<<nb_e, 256, 0, stream>>>(dst, deg, E);
    k_scan1  <<<nb_n, 256, 0, stream>>>(deg, rowptr, bsum, n);
    k_scan2  <<<(n+1+255)/256, 256, 0, stream>>>(rowptr, bsum, n, E);
    k_scatter<<<nb_e, 256, 0, stream>>>(src, dst, rowptr, deg, adj, E);

    k_gemm1  <<<((n+63)/64)*4, 256, 0, stream>>>(x, W1, al1, ar1, ft1h, el1, er1, n);

    int aggBlocks = 1250;                 // 8 waves/block; wave handles nodes {i, i+10000}
    k_agg1   <<<aggBlocks, 512, 0, stream>>>(ft1h, el1, er1, W2, al2, ar2,
                                             rowptr, adj, ft2h, el2, er2,
                                             n, aggBlocks*8);
    k_agg2   <<<(n+3)/4, 256, 0, stream>>>(ft2h, el2, er2, rowptr, adj,
                                           (float*)d_out, n);
}

// Round 14
// 219.453 us; speedup vs baseline: 1.1678x; 1.1678x over previous
//
#include <hip/hip_runtime.h>
#include <hip/hip_fp16.h>

#define FIN 128
#define F1 256      // H1*D1
#define H1N 8
#define D1N 32
#define NCLS 40
#define FT2P 64     // padded row stride for ft2 (halves)
#define W2PITCH 258 // LDS pitch (halves) >= 256! dword-bank=(c+2k)%32 -> worst 2-way (free)
#define NEG 0.2f

static __device__ __forceinline__ float leaky(float x){ return x >= 0.f ? x : NEG*x; }

// ---------------- CSR build ----------------
__global__ void k_hist(const int* __restrict__ dst, int* __restrict__ deg, int E){
    int e = blockIdx.x*256 + threadIdx.x;
    if (e < E) atomicAdd(&deg[dst[e]], 1);
}

__global__ void k_scan1(const int* __restrict__ deg, int* __restrict__ rowptr,
                        int* __restrict__ bsum, int n){
    __shared__ int s[256];
    int t = threadIdx.x;
    int i = blockIdx.x*256 + t;
    int v = (i < n) ? deg[i] : 0;
    s[t] = v;
    __syncthreads();
    for (int off=1; off<256; off<<=1){
        int y = (t >= off) ? s[t-off] : 0;
        __syncthreads();
        if (t >= off) s[t] += y;
        __syncthreads();
    }
    if (i < n) rowptr[i] = s[t] - v;          // exclusive, pre-offset
    if (t == 255) bsum[blockIdx.x] = s[255];
}

__global__ void k_scan2(int* __restrict__ rowptr, const int* __restrict__ bsum,
                        int n, int E){
    int b = blockIdx.x;
    int l = threadIdx.x & 63;
    int v = 0;
    for (int j = l; j < b; j += 64) v += bsum[j];
    for (int msk=1; msk<64; msk<<=1) v += __shfl_xor(v, msk);
    int i = b*256 + threadIdx.x;
    if (i < n) rowptr[i] += v;
    else if (i == n) rowptr[n] = E;
}

__global__ void k_scatter(const int* __restrict__ src, const int* __restrict__ dst,
                          const int* __restrict__ rowptr, int* __restrict__ deg,
                          int* __restrict__ adj, int* __restrict__ did, int E){
    int e = blockIdx.x*256 + threadIdx.x;
    if (e < E){
        int d = dst[e];
        int pos = atomicSub(&deg[d], 1) - 1;
        int q = rowptr[d] + pos;
        adj[q] = src[e];
        did[q] = d;
    }
}

// ---------------- GEMM1: [M,128]@[128,256] -> fp16 FT + fused el/er ----------------
__global__ __launch_bounds__(256) void k_gemm1(const float* __restrict__ X,
                                               const float* __restrict__ W,
                                               const float* __restrict__ al,
                                               const float* __restrict__ ar,
                                               __half* __restrict__ FT,
                                               float* __restrict__ el,
                                               float* __restrict__ er, int M){
    __shared__ float As[32][68];   // As[k][m]
    __shared__ float Bs[32][68];   // Bs[k][n]
    int t = threadIdx.x;
    int bx = blockIdx.x & 3;
    int by = blockIdx.x >> 2;
    int m0 = by*64, n0 = bx*64;
    int ty = t >> 4, tx = t & 15;
    float acc[4][4] = {};
    for (int k0 = 0; k0 < FIN; k0 += 32){
        #pragma unroll
        for (int p=0;p<2;p++){
            int f = t + p*256;
            int m = f >> 3;
            int kq = f & 7;
            int row = m0 + m;
            float4 v = make_float4(0.f,0.f,0.f,0.f);
            if (row < M) v = *(const float4*)&X[row*FIN + k0 + kq*4];
            As[kq*4+0][m] = v.x; As[kq*4+1][m] = v.y;
            As[kq*4+2][m] = v.z; As[kq*4+3][m] = v.w;
        }
        #pragma unroll
        for (int p=0;p<2;p++){
            int f = t + p*256;
            int kk = f >> 4;
            int nq = f & 15;
            float4 v = *(const float4*)&W[(size_t)(k0+kk)*F1 + n0 + nq*4];
            *(float4*)&Bs[kk][nq*4] = v;
        }
        __syncthreads();
        #pragma unroll
        for (int kk=0; kk<32; kk++){
            float4 a4 = *(const float4*)&As[kk][ty*4];
            float4 b4 = *(const float4*)&Bs[kk][tx*4];
            float av[4] = {a4.x,a4.y,a4.z,a4.w};
            float bv[4] = {b4.x,b4.y,b4.z,b4.w};
            #pragma unroll
            for (int r=0;r<4;r++)
                #pragma unroll
                for (int c=0;c<4;c++)
                    acc[r][c] = fmaf(av[r], bv[c], acc[r][c]);
        }
        __syncthreads();
    }
    // fused el/er: head h spans 32 cols; this thread's 4 cols lie in one head
    int h = (bx<<1) + (tx>>3);
    int basew = h*D1N + (tx&7)*4;
    float4 wl = *(const float4*)&al[basew];
    float4 wr = *(const float4*)&ar[basew];
    float pl[4], pr[4];
    #pragma unroll
    for (int r=0;r<4;r++){
        pl[r] = acc[r][0]*wl.x + acc[r][1]*wl.y + acc[r][2]*wl.z + acc[r][3]*wl.w;
        pr[r] = acc[r][0]*wr.x + acc[r][1]*wr.y + acc[r][2]*wr.z + acc[r][3]*wr.w;
    }
    #pragma unroll
    for (int msk=1; msk<8; msk<<=1){
        #pragma unroll
        for (int r=0;r<4;r++){
            pl[r] += __shfl_xor(pl[r], msk);
            pr[r] += __shfl_xor(pr[r], msk);
        }
    }
    #pragma unroll
    for (int r=0;r<4;r++){
        int row = m0 + ty*4 + r;
        if (row < M){
            union { uint2 u; __half2 h2[2]; } P;
            P.h2[0] = __floats2half2_rn(acc[r][0], acc[r][1]);
            P.h2[1] = __floats2half2_rn(acc[r][2], acc[r][3]);
            *(uint2*)&FT[(size_t)row*F1 + n0 + tx*4] = P.u;
            if ((tx & 7) == 0){
                el[row*H1N + h] = pl[r];
                er[row*H1N + h] = pr[r];
            }
        }
    }
}

// ---- alpha precompute layer 1: edge(CSR-position)-parallel, no dependent chains ----
__global__ __launch_bounds__(256) void k_alpha1(const float* __restrict__ el,
                      const float* __restrict__ er, const int* __restrict__ adj,
                      const int* __restrict__ did, __half* __restrict__ alph, int E){
    int p = blockIdx.x*256 + threadIdx.x;
    if (p >= E) return;
    int s = adj[p], d = did[p];
    float4 e0 = *(const float4*)&el[s*H1N];
    float4 e1 = *(const float4*)&el[s*H1N + 4];
    float4 r0 = *(const float4*)&er[d*H1N];
    float4 r1 = *(const float4*)&er[d*H1N + 4];
    union { uint4 u; __half2 h[4]; } O;
    O.h[0] = __floats2half2_rn(__expf(leaky(e0.x+r0.x)), __expf(leaky(e0.y+r0.y)));
    O.h[1] = __floats2half2_rn(__expf(leaky(e0.z+r0.z)), __expf(leaky(e0.w+r0.w)));
    O.h[2] = __floats2half2_rn(__expf(leaky(e1.x+r1.x)), __expf(leaky(e1.y+r1.y)));
    O.h[3] = __floats2half2_rn(__expf(leaky(e1.z+r1.z)), __expf(leaky(e1.w+r1.w)));
    *(uint4*)&alph[(size_t)p*H1N] = O.u;
}

// ---- alpha precompute layer 2 ----
__global__ __launch_bounds__(256) void k_alpha2(const float* __restrict__ el2,
                      const float* __restrict__ er2, const int* __restrict__ adj,
                      const int* __restrict__ did, __half* __restrict__ alph2, int E){
    int p = blockIdx.x*256 + threadIdx.x;
    if (p >= E) return;
    alph2[p] = __float2half_rn(__expf(leaky(el2[adj[p]] + er2[did[p]])));
}

// ---- layer-1 agg + relu + fused GEMM2/el2/er2; alpha precomputed (2-stage chain) ----
__global__ __launch_bounds__(512) void k_agg1(const __half* __restrict__ FT,
                      const __half* __restrict__ alph,
                      const float* __restrict__ W2,      // [256][40] fp32
                      const float* __restrict__ al2, const float* __restrict__ ar2,
                      const int* __restrict__ rowptr, const int* __restrict__ adj,
                      __half* __restrict__ FT2, float* __restrict__ el2,
                      float* __restrict__ er2, int n, int nwTot){
    __shared__ __half W2h[40*W2PITCH];   // transposed: W2h[c][k], ~20.2 KB
    __shared__ float  hst[8][260];       // per-wave h-row staging
    int t = threadIdx.x;
    for (int e = t; e < 256*40; e += 512){
        int k = e / 40, c = e - k*40;
        W2h[c*W2PITCH + k] = __float2half_rn(W2[e]);
    }
    __syncthreads();

    int w = t >> 6, l = t & 63;
    int h2 = l >> 3;                   // head owning elements [4l,4l+4)
    int c = (l < 40) ? l : (l - 40);
    float keep = (l < NCLS) ? 1.f : 0.f;
    float a2l = al2[c], a2r = ar2[c];
    const __half* wrow = &W2h[c*W2PITCH];
    float* hp = &hst[w][0];

    for (int node = blockIdx.x*8 + w; node < n; node += nwTot){
        int rs = rowptr[node];
        int deg = rowptr[node+1] - rs;

        float ssum = 0.f;
        float ax=0.f, ay=0.f, az=0.f, aw=0.f;
        int j = 0;
        for (; j + 8 <= deg; j += 8){
            int sv[8];
            #pragma unroll
            for (int i=0;i<8;i++) sv[i] = adj[rs+j+i];
            float av[8];
            #pragma unroll
            for (int i=0;i<8;i++){              // position-indexed: independent of adj
                av[i] = __half2float(alph[(size_t)(rs+j+i)*H1N + h2]);
                ssum += av[i];
            }
            #pragma unroll
            for (int i=0;i<8;i++){
                union { uint2 u; __half2 h2v[2]; } U;
                U.u = *(const uint2*)&FT[(size_t)sv[i]*F1 + l*4];
                float2 f01 = __half22float2(U.h2v[0]);
                float2 f23 = __half22float2(U.h2v[1]);
                ax = fmaf(av[i], f01.x, ax); ay = fmaf(av[i], f01.y, ay);
                az = fmaf(av[i], f23.x, az); aw = fmaf(av[i], f23.y, aw);
            }
        }
        for (; j < deg; j++){
            int s = adj[rs + j];
            float a = __half2float(alph[(size_t)(rs+j)*H1N + h2]);
            ssum += a;
            union { uint2 u; __half2 h2v[2]; } U;
            U.u = *(const uint2*)&FT[(size_t)s*F1 + l*4];
            float2 f01 = __half22float2(U.h2v[0]);
            float2 f23 = __half22float2(U.h2v[1]);
            ax = fmaf(a, f01.x, ax); ay = fmaf(a, f01.y, ay);
            az = fmaf(a, f23.x, az); aw = fmaf(a, f23.y, aw);
        }
        float inv = 1.f / fmaxf(ssum, 1e-16f);
        ax = fmaxf(ax*inv, 0.f); ay = fmaxf(ay*inv, 0.f);
        az = fmaxf(az*inv, 0.f); aw = fmaxf(aw*inv, 0.f);

        // ---- fused GEMM2 epilogue: out[c] = sum_k h[k] * W2[k][c] ----
        *(float4*)&hp[l*4] = make_float4(ax, ay, az, aw);
        __builtin_amdgcn_wave_barrier();
        asm volatile("s_waitcnt lgkmcnt(0)" ::: "memory");
        float o0=0.f, o1=0.f, o2=0.f, o3=0.f;   // 4 independent chains
        #pragma unroll
        for (int k0 = 0; k0 < 64; k0 += 4){
            {   float4 hv = *(const float4*)&hp[k0*4];
                float2 fa = __half22float2(*(const __half2*)&wrow[k0*4]);
                float2 fb = __half22float2(*(const __half2*)&wrow[k0*4+2]);
                o0 = fmaf(hv.x, fa.x, o0); o0 = fmaf(hv.y, fa.y, o0);
                o0 = fmaf(hv.z, fb.x, o0); o0 = fmaf(hv.w, fb.y, o0); }
            {   float4 hv = *(const float4*)&hp[(k0+1)*4];
                float2 fa = __half22float2(*(const __half2*)&wrow[(k0+1)*4]);
                float2 fb = __half22float2(*(const __half2*)&wrow[(k0+1)*4+2]);
                o1 = fmaf(hv.x, fa.x, o1); o1 = fmaf(hv.y, fa.y, o1);
                o1 = fmaf(hv.z, fb.x, o1); o1 = fmaf(hv.w, fb.y, o1); }
            {   float4 hv = *(const float4*)&hp[(k0+2)*4];
                float2 fa = __half22float2(*(const __half2*)&wrow[(k0+2)*4]);
                float2 fb = __half22float2(*(const __half2*)&wrow[(k0+2)*4+2]);
                o2 = fmaf(hv.x, fa.x, o2); o2 = fmaf(hv.y, fa.y, o2);
                o2 = fmaf(hv.z, fb.x, o2); o2 = fmaf(hv.w, fb.y, o2); }
            {   float4 hv = *(const float4*)&hp[(k0+3)*4];
                float2 fa = __half22float2(*(const __half2*)&wrow[(k0+3)*4]);
                float2 fb = __half22float2(*(const __half2*)&wrow[(k0+3)*4+2]);
                o3 = fmaf(hv.x, fa.x, o3); o3 = fmaf(hv.y, fa.y, o3);
                o3 = fmaf(hv.w, fb.y, o3); o3 = fmaf(hv.z, fb.x, o3); }
        }
        float out = (o0 + o1) + (o2 + o3);
        __builtin_amdgcn_wave_barrier();   // keep next iter's hst write behind these reads
        float pl = keep * out * a2l;
        float pr = keep * out * a2r;
        #pragma unroll
        for (int msk=1; msk<64; msk<<=1){
            pl += __shfl_xor(pl, msk);
            pr += __shfl_xor(pr, msk);
        }
        if (l == 0){ el2[node] = pl; er2[node] = pr; }
        if (l < NCLS) FT2[(size_t)node*FT2P + l] = __float2half_rn(out);
    }
}

// ---------------- layer-2 aggregation; alpha2 precomputed ----------------
__global__ __launch_bounds__(256) void k_agg2(const __half* __restrict__ FT2,
                      const __half* __restrict__ alph2,
                      const int* __restrict__ rowptr, const int* __restrict__ adj,
                      float* __restrict__ out, int n){
    int node = (blockIdx.x*256 + threadIdx.x) >> 6;
    int l = threadIdx.x & 63;
    if (node >= n) return;
    int rs = rowptr[node];
    int deg = rowptr[node+1] - rs;
    float ssum = 0.f, acc = 0.f;
    int j = 0;
    for (; j + 8 <= deg; j += 8){
        int sv[8];
        #pragma unroll
        for (int i=0;i<8;i++) sv[i] = adj[rs+j+i];
        float av[8];
        #pragma unroll
        for (int i=0;i<8;i++){                  // coalesced, independent of adj
            av[i] = __half2float(alph2[rs+j+i]);
            ssum += av[i];
        }
        if (l < NCLS){
            #pragma unroll
            for (int i=0;i<8;i++){
                float f = __half2float(FT2[(size_t)sv[i]*FT2P + l]);
                acc = fmaf(av[i], f, acc);
            }
        }
    }
    for (; j < deg; j++){
        int s = adj[rs + j];
        float a = __half2float(alph2[rs+j]);
        ssum += a;
        if (l < NCLS) acc = fmaf(a, __half2float(FT2[(size_t)s*FT2P + l]), acc);
    }
    if (l < NCLS) out[(size_t)node*NCLS + l] = acc / fmaxf(ssum, 1e-16f);
}

extern "C" void kernel_launch(void* const* d_in, const int* in_sizes, int n_in,
                              void* d_out, int out_size, void* d_ws, size_t ws_size,
                              hipStream_t stream){
    const float* x   = (const float*)d_in[0];
    const float* W1  = (const float*)d_in[1];
    const float* al1 = (const float*)d_in[2];
    const float* ar1 = (const float*)d_in[3];
    const float* W2  = (const float*)d_in[4];
    const float* al2 = (const float*)d_in[5];
    const float* ar2 = (const float*)d_in[6];
    const int*   src = (const int*)d_in[7];
    const int*   dst = (const int*)d_in[8];
    int E = in_sizes[7];
    int n = in_sizes[0] / FIN;   // 20000

    char* ws = (char*)d_ws;
    size_t off = 0;
    auto alloc = [&](size_t bytes)->void*{
        void* p = ws + off; off += (bytes + 255) & ~(size_t)255; return p;
    };
    __half* ft1h  = (__half*)alloc((size_t)n*F1*2);
    __half* ft2h  = (__half*)alloc((size_t)n*FT2P*2);
    __half* alph  = (__half*)alloc((size_t)E*H1N*2);
    __half* alph2 = (__half*)alloc((size_t)E*2);
    float*  el1   = (float*)alloc((size_t)n*H1N*4);
    float*  er1   = (float*)alloc((size_t)n*H1N*4);
    float*  el2   = (float*)alloc((size_t)n*4);
    float*  er2   = (float*)alloc((size_t)n*4);
    int*    rowptr= (int*)alloc((size_t)(n+1)*4);
    int*    adj   = (int*)alloc((size_t)E*4);
    int*    did   = (int*)alloc((size_t)E*4);
    int*    bsum  = (int*)alloc((size_t)((n+255)/256)*4);
    int*    deg   = (int*)alloc((size_t)n*4);

    int nb_e = (E + 255)/256;
    int nb_n = (n + 255)/256;

    hipMemsetAsync(deg, 0, (size_t)n*4, stream);
    k_hist   <<<nb_e, 256, 0, stream>>>(dst, deg, E);
    k_scan1  <<<nb_n, 256, 0, stream>>>(deg, rowptr, bsum, n);
    k_scan2  <<<(n+1+255)/256, 256, 0, stream>>>(rowptr, bsum, n, E);
    k_scatter<<<nb_e, 256, 0, stream>>>(src, dst, rowptr, deg, adj, did, E);

    k_gemm1  <<<((n+63)/64)*4, 256, 0, stream>>>(x, W1, al1, ar1, ft1h, el1, er1, n);
    k_alpha1 <<<nb_e, 256, 0, stream>>>(el1, er1, adj, did, alph, E);

    int aggBlocks = 1250;                 // 8 waves/block, grid-stride over nodes
    k_agg1   <<<aggBlocks, 512, 0, stream>>>(ft1h, alph, W2, al2, ar2,
                                             rowptr, adj, ft2h, el2, er2,
                                             n, aggBlocks*8);
    k_alpha2 <<<nb_e, 256, 0, stream>>>(el2, er2, adj, did, alph2, E);
    k_agg2   <<<(n+3)/4, 256, 0, stream>>>(ft2h, alph2, rowptr, adj,
                                           (float*)d_out, n);
}

// Round 15
// 207.430 us; speedup vs baseline: 1.2355x; 1.0580x over previous
//
#include <hip/hip_runtime.h>
#include <hip/hip_fp16.h>

#define FIN 128
#define F1 256      // H1*D1
#define H1N 8
#define D1N 32
#define NCLS 40
#define FT2P 64     // padded row stride for ft2 (halves)
#define W2PITCH 258 // LDS pitch (halves) >= 256! dword-bank=(c+2k)%32 -> worst 2-way (free)
#define NEG 0.2f

static __device__ __forceinline__ float leaky(float x){ return x >= 0.f ? x : NEG*x; }

// ---------------- CSR build ----------------
__global__ void k_hist(const int* __restrict__ dst, int* __restrict__ deg, int E){
    int e = blockIdx.x*256 + threadIdx.x;
    if (e < E) atomicAdd(&deg[dst[e]], 1);
}

__global__ void k_scan1(const int* __restrict__ deg, int* __restrict__ rowptr,
                        int* __restrict__ bsum, int n){
    __shared__ int s[256];
    int t = threadIdx.x;
    int i = blockIdx.x*256 + t;
    int v = (i < n) ? deg[i] : 0;
    s[t] = v;
    __syncthreads();
    for (int off=1; off<256; off<<=1){
        int y = (t >= off) ? s[t-off] : 0;
        __syncthreads();
        if (t >= off) s[t] += y;
        __syncthreads();
    }
    if (i < n) rowptr[i] = s[t] - v;          // exclusive, pre-offset
    if (t == 255) bsum[blockIdx.x] = s[255];
}

__global__ void k_scan2(int* __restrict__ rowptr, const int* __restrict__ bsum,
                        int n, int E){
    int b = blockIdx.x;
    int l = threadIdx.x & 63;
    int v = 0;
    for (int j = l; j < b; j += 64) v += bsum[j];
    for (int msk=1; msk<64; msk<<=1) v += __shfl_xor(v, msk);
    int i = b*256 + threadIdx.x;
    if (i < n) rowptr[i] += v;
    else if (i == n) rowptr[n] = E;
}

__global__ void k_scatter(const int* __restrict__ src, const int* __restrict__ dst,
                          const int* __restrict__ rowptr, int* __restrict__ deg,
                          int* __restrict__ adj, int E){
    int e = blockIdx.x*256 + threadIdx.x;
    if (e < E){
        int d = dst[e];
        int pos = atomicSub(&deg[d], 1) - 1;
        adj[rowptr[d] + pos] = src[e];
    }
}

// ---------------- GEMM1: [M,128]@[128,256] -> fp16 FT + fused el/er ----------------
__global__ __launch_bounds__(256) void k_gemm1(const float* __restrict__ X,
                                               const float* __restrict__ W,
                                               const float* __restrict__ al,
                                               const float* __restrict__ ar,
                                               __half* __restrict__ FT,
                                               float* __restrict__ el,
                                               float* __restrict__ er, int M){
    __shared__ float As[32][68];   // As[k][m]
    __shared__ float Bs[32][68];   // Bs[k][n]
    int t = threadIdx.x;
    int bx = blockIdx.x & 3;
    int by = blockIdx.x >> 2;
    int m0 = by*64, n0 = bx*64;
    int ty = t >> 4, tx = t & 15;
    float acc[4][4] = {};
    for (int k0 = 0; k0 < FIN; k0 += 32){
        #pragma unroll
        for (int p=0;p<2;p++){
            int f = t + p*256;
            int m = f >> 3;
            int kq = f & 7;
            int row = m0 + m;
            float4 v = make_float4(0.f,0.f,0.f,0.f);
            if (row < M) v = *(const float4*)&X[row*FIN + k0 + kq*4];
            As[kq*4+0][m] = v.x; As[kq*4+1][m] = v.y;
            As[kq*4+2][m] = v.z; As[kq*4+3][m] = v.w;
        }
        #pragma unroll
        for (int p=0;p<2;p++){
            int f = t + p*256;
            int kk = f >> 4;
            int nq = f & 15;
            float4 v = *(const float4*)&W[(size_t)(k0+kk)*F1 + n0 + nq*4];
            *(float4*)&Bs[kk][nq*4] = v;
        }
        __syncthreads();
        #pragma unroll
        for (int kk=0; kk<32; kk++){
            float4 a4 = *(const float4*)&As[kk][ty*4];
            float4 b4 = *(const float4*)&Bs[kk][tx*4];
            float av[4] = {a4.x,a4.y,a4.z,a4.w};
            float bv[4] = {b4.x,b4.y,b4.z,b4.w};
            #pragma unroll
            for (int r=0;r<4;r++)
                #pragma unroll
                for (int c=0;c<4;c++)
                    acc[r][c] = fmaf(av[r], bv[c], acc[r][c]);
        }
        __syncthreads();
    }
    // fused el/er: head h spans 32 cols; this thread's 4 cols lie in one head
    int h = (bx<<1) + (tx>>3);
    int basew = h*D1N + (tx&7)*4;
    float4 wl = *(const float4*)&al[basew];
    float4 wr = *(const float4*)&ar[basew];
    float pl[4], pr[4];
    #pragma unroll
    for (int r=0;r<4;r++){
        pl[r] = acc[r][0]*wl.x + acc[r][1]*wl.y + acc[r][2]*wl.z + acc[r][3]*wl.w;
        pr[r] = acc[r][0]*wr.x + acc[r][1]*wr.y + acc[r][2]*wr.z + acc[r][3]*wr.w;
    }
    #pragma unroll
    for (int msk=1; msk<8; msk<<=1){
        #pragma unroll
        for (int r=0;r<4;r++){
            pl[r] += __shfl_xor(pl[r], msk);
            pr[r] += __shfl_xor(pr[r], msk);
        }
    }
    #pragma unroll
    for (int r=0;r<4;r++){
        int row = m0 + ty*4 + r;
        if (row < M){
            union { uint2 u; __half2 h2[2]; } P;
            P.h2[0] = __floats2half2_rn(acc[r][0], acc[r][1]);
            P.h2[1] = __floats2half2_rn(acc[r][2], acc[r][3]);
            *(uint2*)&FT[(size_t)row*F1 + n0 + tx*4] = P.u;
            if ((tx & 7) == 0){
                el[row*H1N + h] = pl[r];
                er[row*H1N + h] = pr[r];
            }
        }
    }
}

// ---- layer-1 single-pass softmax + agg + relu + fused GEMM2/el2/er2 ----
// persistent grid: exactly 4 blocks/CU x 256 CUs -> no partial dispatch round
__global__ __launch_bounds__(512) void k_agg1(const __half* __restrict__ FT,
                      const float* __restrict__ el, const float* __restrict__ er,
                      const float* __restrict__ W2,      // [256][40] fp32
                      const float* __restrict__ al2, const float* __restrict__ ar2,
                      const int* __restrict__ rowptr, const int* __restrict__ adj,
                      __half* __restrict__ FT2, float* __restrict__ el2,
                      float* __restrict__ er2, int n, int nwTot){
    __shared__ __half W2h[40*W2PITCH];   // transposed: W2h[c][k], ~20.2 KB
    __shared__ float  hst[8][260];       // per-wave h-row staging
    int t = threadIdx.x;
    for (int e = t; e < 256*40; e += 512){
        int k = e / 40, c = e - k*40;
        W2h[c*W2PITCH + k] = __float2half_rn(W2[e]);
    }
    __syncthreads();

    int w = t >> 6, l = t & 63;
    int h2 = l >> 3;                   // head owning elements [4l,4l+4)
    int c = (l < 40) ? l : (l - 40);
    float keep = (l < NCLS) ? 1.f : 0.f;
    float a2l = al2[c], a2r = ar2[c];
    const __half* wrow = &W2h[c*W2PITCH];
    float* hp = &hst[w][0];

    for (int node = blockIdx.x*8 + w; node < n; node += nwTot){
        int rs = rowptr[node];
        int deg = rowptr[node+1] - rs;
        float erh2 = er[node*H1N + h2];

        float ssum = 0.f;
        float ax=0.f, ay=0.f, az=0.f, aw=0.f;
        int j = 0;
        for (; j + 8 <= deg; j += 8){
            int sv[8];
            #pragma unroll
            for (int i=0;i<8;i++) sv[i] = adj[rs+j+i];
            float av[8];
            #pragma unroll
            for (int i=0;i<8;i++){
                av[i] = __expf(leaky(el[sv[i]*H1N + h2] + erh2));
                ssum += av[i];
            }
            #pragma unroll
            for (int i=0;i<8;i++){
                union { uint2 u; __half2 h2v[2]; } U;
                U.u = *(const uint2*)&FT[(size_t)sv[i]*F1 + l*4];
                float2 f01 = __half22float2(U.h2v[0]);
                float2 f23 = __half22float2(U.h2v[1]);
                ax = fmaf(av[i], f01.x, ax); ay = fmaf(av[i], f01.y, ay);
                az = fmaf(av[i], f23.x, az); aw = fmaf(av[i], f23.y, aw);
            }
        }
        for (; j < deg; j++){
            int s = adj[rs + j];
            float a = __expf(leaky(el[s*H1N + h2] + erh2));
            ssum += a;
            union { uint2 u; __half2 h2v[2]; } U;
            U.u = *(const uint2*)&FT[(size_t)s*F1 + l*4];
            float2 f01 = __half22float2(U.h2v[0]);
            float2 f23 = __half22float2(U.h2v[1]);
            ax = fmaf(a, f01.x, ax); ay = fmaf(a, f01.y, ay);
            az = fmaf(a, f23.x, az); aw = fmaf(a, f23.y, aw);
        }
        float inv = 1.f / fmaxf(ssum, 1e-16f);
        ax = fmaxf(ax*inv, 0.f); ay = fmaxf(ay*inv, 0.f);
        az = fmaxf(az*inv, 0.f); aw = fmaxf(aw*inv, 0.f);

        // ---- fused GEMM2 epilogue: out[c] = sum_k h[k] * W2[k][c] ----
        *(float4*)&hp[l*4] = make_float4(ax, ay, az, aw);
        __builtin_amdgcn_wave_barrier();
        asm volatile("s_waitcnt lgkmcnt(0)" ::: "memory");
        float o0=0.f, o1=0.f, o2=0.f, o3=0.f;   // 4 independent chains
        #pragma unroll
        for (int k0 = 0; k0 < 64; k0 += 4){
            {   float4 hv = *(const float4*)&hp[k0*4];
                float2 fa = __half22float2(*(const __half2*)&wrow[k0*4]);
                float2 fb = __half22float2(*(const __half2*)&wrow[k0*4+2]);
                o0 = fmaf(hv.x, fa.x, o0); o0 = fmaf(hv.y, fa.y, o0);
                o0 = fmaf(hv.z, fb.x, o0); o0 = fmaf(hv.w, fb.y, o0); }
            {   float4 hv = *(const float4*)&hp[(k0+1)*4];
                float2 fa = __half22float2(*(const __half2*)&wrow[(k0+1)*4]);
                float2 fb = __half22float2(*(const __half2*)&wrow[(k0+1)*4+2]);
                o1 = fmaf(hv.x, fa.x, o1); o1 = fmaf(hv.y, fa.y, o1);
                o1 = fmaf(hv.z, fb.x, o1); o1 = fmaf(hv.w, fb.y, o1); }
            {   float4 hv = *(const float4*)&hp[(k0+2)*4];
                float2 fa = __half22float2(*(const __half2*)&wrow[(k0+2)*4]);
                float2 fb = __half22float2(*(const __half2*)&wrow[(k0+2)*4+2]);
                o2 = fmaf(hv.x, fa.x, o2); o2 = fmaf(hv.y, fa.y, o2);
                o2 = fmaf(hv.z, fb.x, o2); o2 = fmaf(hv.w, fb.y, o2); }
            {   float4 hv = *(const float4*)&hp[(k0+3)*4];
                float2 fa = __half22float2(*(const __half2*)&wrow[(k0+3)*4]);
                float2 fb = __half22float2(*(const __half2*)&wrow[(k0+3)*4+2]);
                o3 = fmaf(hv.x, fa.x, o3); o3 = fmaf(hv.y, fa.y, o3);
                o3 = fmaf(hv.z, fb.x, o3); o3 = fmaf(hv.w, fb.y, o3); }
        }
        float out = (o0 + o1) + (o2 + o3);
        __builtin_amdgcn_wave_barrier();   // keep next iter's hst write behind these reads
        float pl = keep * out * a2l;
        float pr = keep * out * a2r;
        #pragma unroll
        for (int msk=1; msk<64; msk<<=1){
            pl += __shfl_xor(pl, msk);
            pr += __shfl_xor(pr, msk);
        }
        if (l == 0){ el2[node] = pl; er2[node] = pr; }
        if (l < NCLS) FT2[(size_t)node*FT2P + l] = __float2half_rn(out);
    }
}

// ---------------- layer-2 single-pass softmax + aggregation ----------------
__global__ __launch_bounds__(256) void k_agg2(const __half* __restrict__ FT2,
                      const float* __restrict__ el, const float* __restrict__ er,
                      const int* __restrict__ rowptr, const int* __restrict__ adj,
                      float* __restrict__ out, int n){
    int node = (blockIdx.x*256 + threadIdx.x) >> 6;
    int l = threadIdx.x & 63;
    if (node >= n) return;
    int rs = rowptr[node];
    int deg = rowptr[node+1] - rs;
    float ern = er[node];
    float ssum = 0.f, acc = 0.f;
    int j = 0;
    for (; j + 8 <= deg; j += 8){
        int sv[8];
        #pragma unroll
        for (int i=0;i<8;i++) sv[i] = adj[rs+j+i];
        float av[8];
        #pragma unroll
        for (int i=0;i<8;i++){
            av[i] = __expf(leaky(el[sv[i]] + ern));
            ssum += av[i];
        }
        if (l < NCLS){
            #pragma unroll
            for (int i=0;i<8;i++){
                float f = __half2float(FT2[(size_t)sv[i]*FT2P + l]);
                acc = fmaf(av[i], f, acc);
            }
        }
    }
    for (; j < deg; j++){
        int s = adj[rs + j];
        float a = __expf(leaky(el[s] + ern));
        ssum += a;
        if (l < NCLS) acc = fmaf(a, __half2float(FT2[(size_t)s*FT2P + l]), acc);
    }
    if (l < NCLS) out[(size_t)node*NCLS + l] = acc / fmaxf(ssum, 1e-16f);
}

extern "C" void kernel_launch(void* const* d_in, const int* in_sizes, int n_in,
                              void* d_out, int out_size, void* d_ws, size_t ws_size,
                              hipStream_t stream){
    const float* x   = (const float*)d_in[0];
    const float* W1  = (const float*)d_in[1];
    const float* al1 = (const float*)d_in[2];
    const float* ar1 = (const float*)d_in[3];
    const float* W2  = (const float*)d_in[4];
    const float* al2 = (const float*)d_in[5];
    const float* ar2 = (const float*)d_in[6];
    const int*   src = (const int*)d_in[7];
    const int*   dst = (const int*)d_in[8];
    int E = in_sizes[7];
    int n = in_sizes[0] / FIN;   // 20000

    char* ws = (char*)d_ws;
    size_t off = 0;
    auto alloc = [&](size_t bytes)->void*{
        void* p = ws + off; off += (bytes + 255) & ~(size_t)255; return p;
    };
    __half* ft1h  = (__half*)alloc((size_t)n*F1*2);
    __half* ft2h  = (__half*)alloc((size_t)n*FT2P*2);
    float*  el1   = (float*)alloc((size_t)n*H1N*4);
    float*  er1   = (float*)alloc((size_t)n*H1N*4);
    float*  el2   = (float*)alloc((size_t)n*4);
    float*  er2   = (float*)alloc((size_t)n*4);
    int*    rowptr= (int*)alloc((size_t)(n+1)*4);
    int*    adj   = (int*)alloc((size_t)E*4);
    int*    bsum  = (int*)alloc((size_t)((n+255)/256)*4);
    int*    deg   = (int*)alloc((size_t)n*4);

    int nb_e = (E + 255)/256;
    int nb_n = (n + 255)/256;

    hipMemsetAsync(deg, 0, (size_t)n*4, stream);
    k_hist   <<<nb_e, 256, 0, stream>>>(dst, deg, E);
    k_scan1  <<<nb_n, 256, 0, stream>>>(deg, rowptr, bsum, n);
    k_scan2  <<<(n+1+255)/256, 256, 0, stream>>>(rowptr, bsum, n, E);
    k_scatter<<<nb_e, 256, 0, stream>>>(src, dst, rowptr, deg, adj, E);

    k_gemm1  <<<((n+63)/64)*4, 256, 0, stream>>>(x, W1, al1, ar1, ft1h, el1, er1, n);

    int aggBlocks = 1024;                 // persistent: exactly 4 blocks/CU x 256 CUs
    k_agg1   <<<aggBlocks, 512, 0, stream>>>(ft1h, el1, er1, W2, al2, ar2,
                                             rowptr, adj, ft2h, el2, er2,
                                             n, aggBlocks*8);
    k_agg2   <<<(n+3)/4, 256, 0, stream>>>(ft2h, el2, er2, rowptr, adj,
                                           (float*)d_out, n);
}